// Round 4
// baseline (2243.696 us; speedup 1.0000x reference)
//
#include <hip/hip_runtime.h>
#include <math.h>

#define ALPHA_F 0.1f

typedef __attribute__((ext_vector_type(8))) short short8v;
typedef __attribute__((ext_vector_type(4))) float f32x4;

__device__ __forceinline__ unsigned short f2bf(float f) {
    union { float f; unsigned int u; } v; v.f = f;
    unsigned int u = v.u;
    u += 0x7fffu + ((u >> 16) & 1u);   // round-to-nearest-even
    return (unsigned short)(u >> 16);
}

// ---------------- edge format detection (int64 vs int32) ----------------
__global__ __launch_bounds__(256) void k_detect(const int* __restrict__ ei, int E, int* __restrict__ flag) {
    __shared__ int anynz;
    if (threadIdx.x == 0) anynz = 0;
    __syncthreads();
    int bad = 0;
    for (int i = threadIdx.x; i < 4096; i += 256) {
        int idx = 2 * i + 1;
        if (idx < 2 * E) bad |= ei[idx];
    }
    if (bad) atomicOr(&anynz, 1);
    __syncthreads();
    if (threadIdx.x == 0) flag[0] = (anynz == 0) ? 1 : 0;  // 1 => int64 layout
}

__device__ __forceinline__ int edge_src(const int* ei, int e, int E, int is64) {
    return is64 ? ei[2 * e] : ei[e];
}
__device__ __forceinline__ int edge_dst(const int* ei, int e, int E, int is64) {
    return is64 ? ei[2 * E + 2 * e] : ei[E + e];
}

// ---------------- degree / CSR build ----------------
__global__ __launch_bounds__(256) void k_init(int* __restrict__ degi, int N) {
    int i = blockIdx.x * 256 + threadIdx.x;
    if (i < N) degi[i] = 1;  // deg includes self-loop
}

__global__ __launch_bounds__(256) void k_count(const int* __restrict__ ei, const int* __restrict__ flag,
                                               int E, int* __restrict__ degi) {
    int e = blockIdx.x * 256 + threadIdx.x;
    if (e >= E) return;
    int is64 = flag[0];
    atomicAdd(&degi[edge_dst(ei, e, E, is64)], 1);
}

__global__ __launch_bounds__(256) void k_dinv(const int* __restrict__ degi, float* __restrict__ dinv, int N) {
    int i = blockIdx.x * 256 + threadIdx.x;
    if (i < N) dinv[i] = rsqrtf((float)degi[i]);
}

__global__ __launch_bounds__(256) void k_scanA(const int* __restrict__ degi, int N, int* __restrict__ part) {
    __shared__ int sh[256];
    int i = blockIdx.x * 256 + threadIdx.x;
    int v = (i < N) ? degi[i] - 1 : 0;
    sh[threadIdx.x] = v;
    __syncthreads();
    for (int s = 128; s > 0; s >>= 1) {
        if (threadIdx.x < s) sh[threadIdx.x] += sh[threadIdx.x + s];
        __syncthreads();
    }
    if (threadIdx.x == 0) part[blockIdx.x] = sh[0];
}

__global__ __launch_bounds__(512) void k_scanB(int* __restrict__ part, int nb) {
    __shared__ int sh[512];
    int t = threadIdx.x;
    int v = (t < nb) ? part[t] : 0;
    sh[t] = v;
    __syncthreads();
    for (int off = 1; off < 512; off <<= 1) {
        int u = (t >= off) ? sh[t - off] : 0;
        __syncthreads();
        sh[t] += u;
        __syncthreads();
    }
    if (t < nb) part[t] = sh[t] - v;  // exclusive
}

__global__ __launch_bounds__(256) void k_scanC(const int* __restrict__ degi, int N,
                                               const int* __restrict__ part, int* __restrict__ rowptr) {
    __shared__ int sh[256];
    int t = threadIdx.x;
    int i = blockIdx.x * 256 + t;
    int v = (i < N) ? degi[i] - 1 : 0;
    sh[t] = v;
    __syncthreads();
    for (int off = 1; off < 256; off <<= 1) {
        int u = (t >= off) ? sh[t - off] : 0;
        __syncthreads();
        sh[t] += u;
        __syncthreads();
    }
    if (i <= N) rowptr[i] = sh[t] - v + part[blockIdx.x];
}

// ---------------- bucketed CSR fill ----------------
// bucket b = nodes [256b, 256b+256); edge window [rowptr[256b], rowptr[256(b+1)])
__global__ __launch_bounds__(256) void k_bcur(const int* __restrict__ rowptr, int* __restrict__ bcur,
                                              int nbuck, int N) {
    int b = blockIdx.x * 256 + threadIdx.x;
    if (b < nbuck) bcur[b] = rowptr[min(b << 8, N)];
}

// scatter each edge into its bucket window as packed u32: src | (dst&255)<<20
__global__ __launch_bounds__(256) void k_scatterB(const int* __restrict__ ei, const int* __restrict__ flag,
                                                  int E, int* __restrict__ bcur, unsigned* __restrict__ tmp) {
    int e = blockIdx.x * 256 + threadIdx.x;
    if (e >= E) return;
    int is64 = flag[0];
    int s = edge_src(ei, e, E, is64);
    int d = edge_dst(ei, e, E, is64);
    int p = atomicAdd(&bcur[d >> 8], 1);
    tmp[p] = (unsigned)s | ((unsigned)(d & 255) << 20);
}

// one block per bucket: place edges at final CSR position via LDS cursors
__global__ __launch_bounds__(256) void k_fillC(const unsigned* __restrict__ tmp,
                                               const int* __restrict__ rowptr,
                                               int* __restrict__ col, int N) {
    __shared__ int rp[257];
    __shared__ int cur[256];
    int b = blockIdx.x, t = threadIdx.x;
    int n0 = b << 8;
    int nn = min(256, N - n0);          // nodes in this bucket
    for (int j = t; j <= nn; j += 256) rp[j] = rowptr[n0 + j];
    if (t < nn) cur[t] = 0;
    __syncthreads();
    int ebeg = rp[0], eend = rp[nn];
    for (int i = ebeg + t; i < eend; i += 256) {
        unsigned pk = tmp[i];
        int dl = (int)(pk >> 20);
        int p = rp[dl] + atomicAdd(&cur[dl], 1);
        col[p] = (int)(pk & 0xFFFFFu);
    }
}

// ---------------- weight prep: transpose + fp32->bf16 ----------------
__global__ __launch_bounds__(256) void k_w1prep(const float* __restrict__ W1, unsigned short* __restrict__ w1t) {
    __shared__ float tile[64][65];
    int t = threadIdx.x;
    int k0 = (blockIdx.x >> 2) * 64, n0 = (blockIdx.x & 3) * 64;
#pragma unroll
    for (int i = 0; i < 4; ++i) {
        int r = (t >> 4) + 16 * i;
        int c4 = (t & 15) * 4;
        float4 v = *(const float4*)(W1 + (size_t)(k0 + r) * 256 + n0 + c4);
        tile[r][c4 + 0] = v.x; tile[r][c4 + 1] = v.y;
        tile[r][c4 + 2] = v.z; tile[r][c4 + 3] = v.w;
    }
    __syncthreads();
#pragma unroll
    for (int i = 0; i < 4; ++i) {
        int nrow = (t >> 4) + 16 * i;
        int k4 = (t & 15) * 4;
        ushort4 o;
        o.x = f2bf(tile[k4 + 0][nrow]); o.y = f2bf(tile[k4 + 1][nrow]);
        o.z = f2bf(tile[k4 + 2][nrow]); o.w = f2bf(tile[k4 + 3][nrow]);
        *(ushort4*)(w1t + (size_t)(n0 + nrow) * 512 + k0 + k4) = o;
    }
}

__global__ __launch_bounds__(256) void k_w2prep(const float* __restrict__ W2, unsigned short* __restrict__ w2t) {
    int t = threadIdx.x;
    int c = t & 15, k16 = (t >> 4) * 16;
    unsigned short tmp[16];
#pragma unroll
    for (int j = 0; j < 16; ++j) tmp[j] = f2bf(W2[(size_t)(k16 + j) * 16 + c]);
#pragma unroll
    for (int j = 0; j < 16; ++j) w2t[(size_t)c * 256 + k16 + j] = tmp[j];
}

// ---------------- MFMA MLP: H0 = relu(x@W1+b1)@W2+b2 ; G0 = dinv*H0 ----------------
__global__ __launch_bounds__(256, 3) void k_mlp(const float* __restrict__ x,
        const unsigned short* __restrict__ w1t, const float* __restrict__ b1,
        const unsigned short* __restrict__ w2t, const float* __restrict__ b2,
        const float* __restrict__ dinv, float* __restrict__ H0, float* __restrict__ G0, int N) {
    __shared__ __align__(16) char lds[40960];
    char* xs  = lds;              // [64 rows][128 B]
    char* w1s = lds + 8 * 1024;   // [256 rows][128 B]
    char* h1s = lds;              // [64 rows][512 B]   (phase 2, aliases)

    int t = threadIdx.x;
    int w = t >> 6, l = t & 63;
    int row0 = blockIdx.x * 64;

    f32x4 acc[4][4];
#pragma unroll
    for (int i = 0; i < 4; ++i)
#pragma unroll
        for (int j = 0; j < 4; ++j) acc[i][j] = (f32x4){0.f, 0.f, 0.f, 0.f};

    for (int c = 0; c < 8; ++c) {
        int k0 = c * 64;
        __syncthreads();
        {   // stage xs
            int r = t >> 2, c16 = (t & 3) * 16;
            int gr = row0 + r;
            float vf[16];
            if (gr < N) {
                const float* xp = x + (size_t)gr * 512 + k0 + c16;
#pragma unroll
                for (int q = 0; q < 4; ++q) *(float4*)&vf[q * 4] = *(const float4*)(xp + q * 4);
            } else {
#pragma unroll
                for (int q = 0; q < 16; ++q) vf[q] = 0.f;
            }
            union { unsigned short u[8]; short8v v; } p0, p1;
#pragma unroll
            for (int j = 0; j < 8; ++j) { p0.u[j] = f2bf(vf[j]); p1.u[j] = f2bf(vf[8 + j]); }
            int sw = (r & 7) << 4;
            *(short8v*)(xs + r * 128 + ((2 * c16) ^ sw)) = p0.v;
            *(short8v*)(xs + r * 128 + ((2 * c16 + 16) ^ sw)) = p1.v;
        }
        {   // stage w1s
#pragma unroll
            for (int i = 0; i < 8; ++i) {
                int s = t + 256 * i;
                int n = s >> 3, oct = s & 7;
                const unsigned short* gp = w1t + (size_t)n * 512 + k0 + 8 * (oct ^ (n & 7));
                *(short8v*)(w1s + s * 16) = *(const short8v*)gp;
            }
        }
        __syncthreads();
#pragma unroll
        for (int ks = 0; ks < 2; ++ks) {
            int kb = ks * 64 + 16 * (l >> 4);
            short8v af[4], bfr[4];
#pragma unroll
            for (int mf = 0; mf < 4; ++mf) {
                int m = 16 * mf + (l & 15);
                af[mf] = *(const short8v*)(xs + m * 128 + (kb ^ ((m & 7) << 4)));
            }
#pragma unroll
            for (int nt = 0; nt < 4; ++nt) {
                int n = 64 * w + 16 * nt + (l & 15);
                bfr[nt] = *(const short8v*)(w1s + n * 128 + (kb ^ ((n & 7) << 4)));
            }
#pragma unroll
            for (int mf = 0; mf < 4; ++mf)
#pragma unroll
                for (int nt = 0; nt < 4; ++nt)
                    acc[mf][nt] = __builtin_amdgcn_mfma_f32_16x16x32_bf16(af[mf], bfr[nt], acc[mf][nt], 0, 0, 0);
        }
    }

    __syncthreads();
    float b1v[4];
#pragma unroll
    for (int nt = 0; nt < 4; ++nt) b1v[nt] = b1[64 * w + 16 * nt + (l & 15)];
#pragma unroll
    for (int mf = 0; mf < 4; ++mf)
#pragma unroll
        for (int nt = 0; nt < 4; ++nt)
#pragma unroll
            for (int r = 0; r < 4; ++r) {
                int m = 16 * mf + 4 * (l >> 4) + r;
                int n = 64 * w + 16 * nt + (l & 15);
                float val = fmaxf(acc[mf][nt][r] + b1v[nt], 0.f);
                *(unsigned short*)(h1s + m * 512 + ((2 * n) ^ ((m & 7) << 4))) = f2bf(val);
            }
    __syncthreads();

    f32x4 a2 = (f32x4){0.f, 0.f, 0.f, 0.f};
#pragma unroll
    for (int k2 = 0; k2 < 256; k2 += 32) {
        int kb = 2 * k2 + 16 * (l >> 4);
        int m = 16 * w + (l & 15);
        short8v am = *(const short8v*)(h1s + m * 512 + (kb ^ ((m & 7) << 4)));
        short8v bm = *(const short8v*)(w2t + (size_t)(l & 15) * 256 + k2 + 8 * (l >> 4));
        a2 = __builtin_amdgcn_mfma_f32_16x16x32_bf16(am, bm, a2, 0, 0, 0);
    }
    float b2v = b2[l & 15];
#pragma unroll
    for (int r = 0; r < 4; ++r) {
        int m = 16 * w + 4 * (l >> 4) + r;
        int gr = row0 + m;
        if (gr < N) {
            float hv = a2[r] + b2v;
            size_t idx = (size_t)gr * 16 + (l & 15);
            H0[idx] = hv;
            G0[idx] = dinv[gr] * hv;
        }
    }
}

// ---------------- APPNP iteration: contiguous quarters + 8-deep MLP ----------------
// g = dinv*h.  h_new[d] = 0.9*dinv[d]*(sum_e g[s] + g[d]) + 0.1*h0[d]
__global__ __launch_bounds__(256) void k_prop(const float* __restrict__ gin, const float* __restrict__ h0,
                                              float* __restrict__ outb, const float* __restrict__ dinv,
                                              const int* __restrict__ rowptr, const int* __restrict__ col,
                                              int N, int last) {
    int wid = (blockIdx.x * 256 + threadIdx.x) >> 6;
    if (wid >= N) return;
    int lane = threadIdx.x & 63;
    int sub = lane >> 4, c = lane & 15;
    int beg = rowptr[wid], end = rowptr[wid + 1];
    int cnt = end - beg;
    int b0 = beg + ((cnt * sub) >> 2);
    int b1 = beg + ((cnt * (sub + 1)) >> 2);
    float acc = 0.f;
    int i = b0;
    for (; i + 8 <= b1; i += 8) {
        int s[8];
#pragma unroll
        for (int q = 0; q < 8; ++q) s[q] = col[i + q];
        float v[8];
#pragma unroll
        for (int q = 0; q < 8; ++q) v[q] = gin[(size_t)s[q] * 16 + c];
        acc += ((v[0] + v[1]) + (v[2] + v[3])) + ((v[4] + v[5]) + (v[6] + v[7]));
    }
    for (; i < b1; ++i) acc += gin[(size_t)col[i] * 16 + c];
    acc += __shfl_xor(acc, 16, 64);
    acc += __shfl_xor(acc, 32, 64);
    if (sub == 0) {
        float di = dinv[wid];
        size_t base = (size_t)wid * 16 + c;
        float hnew = 0.9f * di * (acc + gin[base]) + ALPHA_F * h0[base];
        outb[base] = last ? hnew : di * hnew;
    }
}

// ---------------- log_softmax over 16 channels ----------------
__global__ __launch_bounds__(256) void k_lsm(const float* __restrict__ hin, float* __restrict__ out, int N) {
    int gid = blockIdx.x * 256 + threadIdx.x;
    int row = gid >> 4;
    if (row >= N) return;
    float v = hin[gid];
    float m = v;
#pragma unroll
    for (int mask = 1; mask <= 8; mask <<= 1) m = fmaxf(m, __shfl_xor(m, mask, 64));
    float e = __expf(v - m);
    float s = e;
#pragma unroll
    for (int mask = 1; mask <= 8; mask <<= 1) s += __shfl_xor(s, mask, 64);
    out[gid] = v - m - __logf(s);
}

extern "C" void kernel_launch(void* const* d_in, const int* in_sizes, int n_in,
                              void* d_out, int out_size, void* d_ws, size_t ws_size,
                              hipStream_t stream) {
    const float* x  = (const float*)d_in[0];
    const int*   ei = (const int*)d_in[1];
    const float* W1 = (const float*)d_in[2];
    const float* b1 = (const float*)d_in[3];
    const float* W2 = (const float*)d_in[4];
    const float* b2 = (const float*)d_in[5];
    float* out = (float*)d_out;

    int N = in_sizes[0] / 512;  // 100000
    int E = in_sizes[1] / 2;    // 3200000

    size_t off = 0;
    char* w = (char*)d_ws;
    auto alloc = [&](size_t bytes) -> void* {
        void* p = (void*)(w + off);
        off += (bytes + 511) & ~(size_t)511;
        return p;
    };
    int*    flag   = (int*)alloc(4);
    int*    degi   = (int*)alloc((size_t)N * 4);
    float*  dinv   = (float*)alloc((size_t)N * 4);
    int*    rowptr = (int*)alloc((size_t)(N + 1) * 4);
    int*    bcur   = (int*)alloc((size_t)512 * 4);
    int*    part   = (int*)alloc(4096);
    int*    col    = (int*)alloc((size_t)E * 4);
    float*  H0     = (float*)alloc((size_t)N * 16 * 4);
    float*  GA     = (float*)alloc((size_t)N * 16 * 4);
    float*  GB     = (float*)alloc((size_t)N * 16 * 4);
    unsigned short* w1t = (unsigned short*)alloc((size_t)512 * 256 * 2);
    unsigned short* w2t = (unsigned short*)alloc((size_t)256 * 16 * 2);
    unsigned* tmp = (unsigned*)GA;   // 12.8MB bucket-scatter scratch aliases GA+GB (dead until k_mlp)
    (void)ws_size; (void)n_in; (void)out_size;

    int NB = (N + 256) / 256;                  // covers 0..N for scans
    int EB = (E + 255) / 256;
    int MB = (N + 63) / 64;
    int PB = (int)(((size_t)N * 64 + 255) / 256);
    int LB = (N * 16 + 255) / 256;
    int NBUCK = (N + 255) >> 8;                // 391

    k_detect<<<1, 256, 0, stream>>>(ei, E, flag);
    k_init<<<NB, 256, 0, stream>>>(degi, N);
    k_count<<<EB, 256, 0, stream>>>(ei, flag, E, degi);
    k_dinv<<<NB, 256, 0, stream>>>(degi, dinv, N);
    k_scanA<<<NB, 256, 0, stream>>>(degi, N, part);
    k_scanB<<<1, 512, 0, stream>>>(part, NB);
    k_scanC<<<NB, 256, 0, stream>>>(degi, N, part, rowptr);

    k_bcur<<<(NBUCK + 255) / 256, 256, 0, stream>>>(rowptr, bcur, NBUCK, N);
    k_scatterB<<<EB, 256, 0, stream>>>(ei, flag, E, bcur, tmp);
    k_fillC<<<NBUCK, 256, 0, stream>>>(tmp, rowptr, col, N);

    k_w1prep<<<32, 256, 0, stream>>>(W1, w1t);
    k_w2prep<<<1, 256, 0, stream>>>(W2, w2t);
    k_mlp<<<MB, 256, 0, stream>>>(x, w1t, b1, w2t, b2, dinv, H0, GA, N);

    const float* cur = GA;
    for (int k = 0; k < 10; ++k) {
        float* o2 = (k & 1) ? GA : GB;
        k_prop<<<PB, 256, 0, stream>>>(cur, H0, o2, dinv, rowptr, col, N, (k == 9) ? 1 : 0);
        cur = o2;
    }
    k_lsm<<<LB, 256, 0, stream>>>(GA, out, N);
}